// Round 5
// baseline (400.794 us; speedup 1.0000x reference)
//
#include <hip/hip_runtime.h>
#include <cstdint>

#define N_PTS 262144
#define DIM   128
#define K_CL  1024
#define NT    32           // 32 cluster tiles of 32
#define BM    256          // rows per block: 4 waves x 64 rows
#define OFFSET_F 512.0f    // shifts tracked values positive -> float bits uint-sortable
#define TAU_FLAG 0.015f    // flag margin (covers key truncation 7.8e-3 + 6-sigma split error)
#define FLAG_CAP 16384

typedef __bf16 bf16x8 __attribute__((ext_vector_type(8)));
typedef float  f32x4  __attribute__((ext_vector_type(4)));

static __device__ __forceinline__ unsigned umin_(unsigned a, unsigned b) { return a < b ? a : b; }
static __device__ __forceinline__ unsigned umax_(unsigned a, unsigned b) { return a > b ? a : b; }

// ---------- prologue: split centers to bf16 hi/lo + (||c||^2 + OFFSET) ----------
__global__ void prep_centers(const float* __restrict__ C,
                             __bf16* __restrict__ Ch, __bf16* __restrict__ Cl,
                             float* __restrict__ csqB) {
    int w = threadIdx.x >> 6, l = threadIdx.x & 63;
    int k = blockIdx.x * 4 + w;                 // one cluster per wave
    float a = C[k * DIM + l];
    float b = C[k * DIM + 64 + l];
    __bf16 ha = (__bf16)a, hb = (__bf16)b;
    Ch[k * DIM + l]      = ha;
    Ch[k * DIM + 64 + l] = hb;
    Cl[k * DIM + l]      = (__bf16)(a - (float)ha);
    Cl[k * DIM + 64 + l] = (__bf16)(b - (float)hb);
    float s = a * a + b * b;
    #pragma unroll
    for (int off = 32; off; off >>= 1) s += __shfl_xor(s, off, 64);
    if (l == 0) csqB[k] = s + OFFSET_F;
}

// ---------- main fused kernel ----------
#define GLOAD_LDS16(g, p) \
    __builtin_amdgcn_global_load_lds((const __attribute__((address_space(1))) void*)(g), \
                                     (__attribute__((address_space(3))) void*)(p), 16, 0, 0)

__launch_bounds__(256, 2)
__global__ void kmeans_assign(const float* __restrict__ X,
                              const __bf16* __restrict__ Ch,
                              const __bf16* __restrict__ Cl,
                              const float* __restrict__ csqB_g,
                              int* __restrict__ out,
                              int* __restrict__ cnt,
                              int* __restrict__ list) {
    // [buf][hi/lo][8KB]; chunk layout: slot s holds dims [8*(s>>5)..+7] of cluster (s&31)
    __shared__ __align__(16) char  tiles[2][2][8192];
    __shared__ __align__(16) float csq_s[K_CL];

    const int tid = threadIdx.x;
    const int w   = tid >> 6;
    const int l   = tid & 63;
    const int c16 = l & 15;
    const int g4  = l >> 4;

    ((float4*)csq_s)[tid] = ((const float4*)csqB_g)[tid];   // 4 KB

    const int rowbase = blockIdx.x * BM + w * 64;

    // ---- load + split this wave's 64 X rows into register fragments (held all K) ----
    bf16x8 xh[4][4], xl[4][4];        // [row-tile rt][ks]
    #pragma unroll
    for (int rt = 0; rt < 4; ++rt) {
        const float* xr = X + (size_t)(rowbase + rt * 16 + c16) * DIM;
        #pragma unroll
        for (int ks = 0; ks < 4; ++ks) {
            int d0 = ks * 32 + g4 * 8;
            float4 a = *(const float4*)(xr + d0);
            float4 b = *(const float4*)(xr + d0 + 4);
            float xe[8] = {a.x, a.y, a.z, a.w, b.x, b.y, b.z, b.w};
            #pragma unroll
            for (int e = 0; e < 8; ++e) {
                __bf16 h = (__bf16)xe[e];
                xh[rt][ks][e] = h;
                xl[rt][ks][e] = (__bf16)(xe[e] - (float)h);
            }
        }
    }

    // ---- staging source offsets: slot s -> cluster (s&31), dim-chunk (s>>5) ----
    const char* ChB = (const char*)Ch;
    const char* ClB = (const char*)Cl;
    const int s0 = w * 64 + l, s1 = s0 + 256;
    const size_t off0 = (size_t)((s0 & 31) * 256 + (s0 >> 5) * 16);
    const size_t off1 = (size_t)((s1 & 31) * 256 + (s1 >> 5) * 16);

    // prologue stage: tile 0 into buf 0
    GLOAD_LDS16(ChB + off0, &tiles[0][0][w * 1024]);
    GLOAD_LDS16(ChB + off1, &tiles[0][0][w * 1024 + 4096]);
    GLOAD_LDS16(ClB + off0, &tiles[0][1][w * 1024]);
    GLOAD_LDS16(ClB + off1, &tiles[0][1][w * 1024 + 4096]);
    __syncthreads();

    unsigned k1[4][4], k2[4][4];      // sortable-key top-2 per (rt, acc-reg)
    #pragma unroll
    for (int rt = 0; rt < 4; ++rt)
        #pragma unroll
        for (int r = 0; r < 4; ++r) { k1[rt][r] = 0xFFFFFFFFu; k2[rt][r] = 0xFFFFFFFFu; }

    for (int t = 0; t < NT; ++t) {
        const int buf = t & 1;

        // prefetch next tile into the other buffer (in flight across the MFMA phase)
        if (t + 1 < NT) {
            const size_t tb = (size_t)(t + 1) * 8192;
            GLOAD_LDS16(ChB + tb + off0, &tiles[buf ^ 1][0][w * 1024]);
            GLOAD_LDS16(ChB + tb + off1, &tiles[buf ^ 1][0][w * 1024 + 4096]);
            GLOAD_LDS16(ClB + tb + off0, &tiles[buf ^ 1][1][w * 1024]);
            GLOAD_LDS16(ClB + tb + off1, &tiles[buf ^ 1][1][w * 1024 + 4096]);
        }

        const char* hb = tiles[buf][0];
        const char* lb = tiles[buf][1];

        f32x4 acc[4][2];
        #pragma unroll
        for (int rt = 0; rt < 4; ++rt) {
            acc[rt][0] = (f32x4){0.f, 0.f, 0.f, 0.f};
            acc[rt][1] = (f32x4){0.f, 0.f, 0.f, 0.f};
        }

        // 3-pass split GEMM: cross ~= xh*ch + xl*ch + xh*cl  (error sigma ~3e-5)
        #pragma unroll
        for (int ks = 0; ks < 4; ++ks) {
            const int base = ks * 2048 + g4 * 512 + c16 * 16;
            bf16x8 bAh = *(const bf16x8*)(hb + base);
            bf16x8 bBh = *(const bf16x8*)(hb + base + 256);
            bf16x8 bAl = *(const bf16x8*)(lb + base);
            bf16x8 bBl = *(const bf16x8*)(lb + base + 256);
            #pragma unroll
            for (int rt = 0; rt < 4; ++rt) {
                acc[rt][0] = __builtin_amdgcn_mfma_f32_16x16x32_bf16(xh[rt][ks], bAh, acc[rt][0], 0, 0, 0);
                acc[rt][1] = __builtin_amdgcn_mfma_f32_16x16x32_bf16(xh[rt][ks], bBh, acc[rt][1], 0, 0, 0);
                acc[rt][0] = __builtin_amdgcn_mfma_f32_16x16x32_bf16(xl[rt][ks], bAh, acc[rt][0], 0, 0, 0);
                acc[rt][1] = __builtin_amdgcn_mfma_f32_16x16x32_bf16(xl[rt][ks], bBh, acc[rt][1], 0, 0, 0);
                acc[rt][0] = __builtin_amdgcn_mfma_f32_16x16x32_bf16(xh[rt][ks], bAl, acc[rt][0], 0, 0, 0);
                acc[rt][1] = __builtin_amdgcn_mfma_f32_16x16x32_bf16(xh[rt][ks], bBl, acc[rt][1], 0, 0, 0);
            }
        }

        // epilogue: key = (bits(csq+512-2cross) & ~63) | (t*2+sub); track top-2
        const float csqA = csq_s[t * 32 + c16];
        const float csqB = csq_s[t * 32 + 16 + c16];
        const unsigned idxA = (unsigned)(t * 2), idxB = (unsigned)(t * 2 + 1);
        #pragma unroll
        for (int rt = 0; rt < 4; ++rt) {
            #pragma unroll
            for (int r = 0; r < 4; ++r) {
                float vA = fmaf(-2.0f, acc[rt][0][r], csqA);
                unsigned kA = (__float_as_uint(vA) & 0xFFFFFFC0u) | idxA;   // v_and_or_b32
                k2[rt][r] = umin_(k2[rt][r], umax_(kA, k1[rt][r]));
                k1[rt][r] = umin_(k1[rt][r], kA);
                float vB = fmaf(-2.0f, acc[rt][1][r], csqB);
                unsigned kB = (__float_as_uint(vB) & 0xFFFFFFC0u) | idxB;
                k2[rt][r] = umin_(k2[rt][r], umax_(kB, k1[rt][r]));
                k1[rt][r] = umin_(k1[rt][r], kB);
            }
        }

        __syncthreads();   // prefetch landed (vmcnt drain) + all reads of buf done
    }

    // ---- cross-lane top-2 merge over the 16 cluster-columns, flag + store ----
    #pragma unroll
    for (int rt = 0; rt < 4; ++rt) {
        #pragma unroll
        for (int r = 0; r < 4; ++r) {
            unsigned a1 = k1[rt][r], a2 = k2[rt][r];
            unsigned i1 = (a1 & 63u) * 16u + (unsigned)c16;   // = t*32 + sub*16 + c16
            #pragma unroll
            for (int off = 1; off < 16; off <<= 1) {
                unsigned b1 = (unsigned)__shfl_xor((int)a1, off, 16);
                unsigned j1 = (unsigned)__shfl_xor((int)i1, off, 16);
                unsigned b2 = (unsigned)__shfl_xor((int)a2, off, 16);
                bool sw = b1 < a1;                 // strict: ambiguous ties land in the flag path
                unsigned loser = sw ? a1 : b1;
                unsigned w2    = sw ? b2 : a2;     // winner's own 2nd
                a1 = sw ? b1 : a1;
                i1 = sw ? j1 : i1;
                a2 = umin_(loser, w2);
            }
            if (c16 == 0) {
                const int row = rowbase + rt * 16 + g4 * 4 + r;
                out[row] = (int)i1;                // int32 labels
                float v1 = __uint_as_float(a1 & 0xFFFFFFC0u);
                float v2 = __uint_as_float(a2 & 0xFFFFFFC0u);
                if (v2 - v1 < TAU_FLAG) {
                    int pos = atomicAdd(cnt, 1);
                    if (pos < FLAG_CAP) list[pos] = row;
                }
            }
        }
    }
}

// ---------- exact fp32 fallback for flagged rows (full 1024-cluster rescan) ----------
__launch_bounds__(256)
__global__ void exact_fallback(const float* __restrict__ X,
                               const float* __restrict__ C,
                               const int* __restrict__ cnt,
                               const int* __restrict__ list,
                               int* __restrict__ out) {
    __shared__ __align__(16) float xs[4][128];
    const int tid = threadIdx.x;
    const int w = tid >> 6, l = tid & 63;
    const int gw = blockIdx.x * 4 + w;
    const int nw = gridDim.x * 4;

    int n = *cnt;
    if (n > FLAG_CAP) n = FLAG_CAP;

    for (int i = gw; i < n; i += nw) {
        const int row = list[i];
        const float* xr = X + (size_t)row * DIM;
        xs[w][l]      = xr[l];
        xs[w][l + 64] = xr[l + 64];
        asm volatile("s_waitcnt lgkmcnt(0)" ::: "memory");   // same-wave LDS visibility

        const float4* xv4 = (const float4*)xs[w];
        float4 px = {0.f, 0.f, 0.f, 0.f};
        #pragma unroll
        for (int j = 0; j < 32; ++j) {
            float4 xv = xv4[j];
            px.x = fmaf(xv.x, xv.x, px.x); px.y = fmaf(xv.y, xv.y, px.y);
            px.z = fmaf(xv.z, xv.z, px.z); px.w = fmaf(xv.w, xv.w, px.w);
        }
        const float x_sq = (px.x + px.y) + (px.z + px.w);

        float bv = 3.0e38f; int bi = 0x7FFFFFFF;
        for (int c = l * 16; c < l * 16 + 16; ++c) {
            const float4* cp = (const float4*)(C + (size_t)c * DIM);
            float4 pc = {0.f, 0.f, 0.f, 0.f}, pd = {0.f, 0.f, 0.f, 0.f};
            #pragma unroll
            for (int j = 0; j < 32; ++j) {
                float4 cv = cp[j];
                float4 xv = xv4[j];
                pc.x = fmaf(cv.x, cv.x, pc.x); pc.y = fmaf(cv.y, cv.y, pc.y);
                pc.z = fmaf(cv.z, cv.z, pc.z); pc.w = fmaf(cv.w, cv.w, pc.w);
                pd.x = fmaf(xv.x, cv.x, pd.x); pd.y = fmaf(xv.y, cv.y, pd.y);
                pd.z = fmaf(xv.z, cv.z, pd.z); pd.w = fmaf(xv.w, cv.w, pd.w);
            }
            float c_sq  = (pc.x + pc.y) + (pc.z + pc.w);
            float cross = (pd.x + pd.y) + (pd.z + pd.w);
            float dis = fmaf(-2.0f, cross, x_sq) + c_sq;   // reference: x2 - 2xc + c2
            if (dis < bv) { bv = dis; bi = c; }            // ascending c: strict < keeps lowest
        }
        #pragma unroll
        for (int off = 32; off; off >>= 1) {
            float ov = __shfl_xor(bv, off, 64);
            int   oi = __shfl_xor(bi, off, 64);
            if (ov < bv || (ov == bv && oi < bi)) { bv = ov; bi = oi; }
        }
        if (l == 0) out[row] = bi;
    }
}

// ---------- launcher ----------
extern "C" void kernel_launch(void* const* d_in, const int* in_sizes, int n_in,
                              void* d_out, int out_size, void* d_ws, size_t ws_size,
                              hipStream_t stream) {
    (void)in_sizes; (void)n_in; (void)out_size; (void)ws_size;
    const float* X = (const float*)d_in[0];
    const float* C = (const float*)d_in[1];
    int* out = (int*)d_out;

    char* ws = (char*)d_ws;
    __bf16* Ch  = (__bf16*)(ws);                       // 256 KB
    __bf16* Cl  = (__bf16*)(ws + (1 << 18));           // 256 KB
    float*  csq = (float*)(ws + (1 << 19));            // 4 KB
    int*    cnt = (int*)(ws + (1 << 19) + 4096);       // 4 B
    int*    lst = (int*)(ws + (1 << 19) + 4096 + 256); // 64 KB

    hipMemsetAsync(cnt, 0, sizeof(int), stream);
    prep_centers<<<K_CL / 4, 256, 0, stream>>>(C, Ch, Cl, csq);
    kmeans_assign<<<N_PTS / BM, 256, 0, stream>>>(X, Ch, Cl, csq, out, cnt, lst);
    exact_fallback<<<256, 256, 0, stream>>>(X, C, cnt, lst, out);
}